// Round 7
// baseline (374.969 us; speedup 1.0000x reference)
//
#include <hip/hip_runtime.h>

#define HW 4096
#define NBLK 512

typedef __attribute__((ext_vector_type(8)))  short short8;
typedef __attribute__((ext_vector_type(16))) float float16;

__device__ __forceinline__ unsigned short f2bf(float f) {
    unsigned u = __float_as_uint(f);
    u += 0x7fffu + ((u >> 16) & 1u);   // RNE
    return (unsigned short)(u >> 16);
}

struct Params {
    const float *x;
    const float *sW, *sb, *s_g, *s_b, *s_m, *s_v;
    const float *cW, *cb, *c_g, *c_b, *c_m, *c_v;
    const float *qW, *qb, *kW, *kb, *vW, *vb, *oW, *ob;
    const float *s_gamma, *c_gamma;
    float *out;
    float *sx, *cx, *Opart, *denp, *ATg, *Gpart, *oWTg, *scsh;
    unsigned *bar;
    unsigned short *qT, *kT, *vB, *Wa;
};

// LDS union across phases; max member = 43520 B -> 2 blocks/CU by LDS.
union SmemAll {
    unsigned short xs[3 * 8 * 66 * 8];                              // conv
    struct { float o_sh[4][64][33]; float den_sh[4][32]; } at;      // attn
    float slab[64][68];                                             // gram
    struct {
        float AT[64][68];
        union {
            float A_raw[64][68];                                    // C2
            struct { float cxs[64][17]; float f_sh[64][17];
                     float oWT[64][68]; } f;                        // D
        } u;
    } d;
};

// Grid barrier: cells come in poisoned 0xAAAAAAAA each launch; first block
// CASes to 0, everyone increments, spin to NBLK. Co-residency guaranteed by
// __launch_bounds__(256,2) (VGPR<=128) + 42.5KB LDS -> 2 blocks/CU.
__device__ __forceinline__ void gridbar(unsigned* cell)
{
    __syncthreads();
    if (threadIdx.x == 0) {
        __threadfence();
        atomicCAS(cell, 0xAAAAAAAAu, 0u);
        atomicAdd(cell, 1u);
        while (atomicAdd(cell, 0u) < NBLK) __builtin_amdgcn_s_sleep(8);
        __threadfence();
    }
    __syncthreads();
}

__global__ __launch_bounds__(256, 2) void k_mega(Params p)
{
    __shared__ SmemAll sm;
    int bx = blockIdx.x;
    int t  = threadIdx.x;

    // ============ Phase A: weight prep ============
    if (bx < 18) {
        int which = bx / 9, khw = bx % 9;
        const float* W = which ? p.cW : p.sW;
#pragma unroll
        for (int i = 0; i < 16; i++) {
            int idx = t + 256 * i;            // 4096 = 64oc x 64ic
            int oc = idx >> 6, ic = idx & 63;
            float v = W[(size_t)(oc * 64 + ic) * 9 + khw];
            p.Wa[((size_t)(which * 9 + khw) * 64 + oc) * 64 + ic] = f2bf(v);
        }
        if (bx == 0 && t < 128) {
            int wh = t >> 6, oc = t & 63;
            const float* g  = wh ? p.c_g : p.s_g;
            const float* bb = wh ? p.c_b : p.s_b;
            const float* m  = wh ? p.c_m : p.s_m;
            const float* vv = wh ? p.c_v : p.s_v;
            const float* cbias = wh ? p.cb : p.sb;
            float scale = g[oc] * rsqrtf(vv[oc] + 1e-5f);
            p.scsh[wh * 128 + oc]      = scale;
            p.scsh[wh * 128 + 64 + oc] = (cbias[oc] - m[oc]) * scale + bb[oc];
        }
    } else if (bx == 18) {
#pragma unroll
        for (int k = 0; k < 16; k++) {
            int idx = t + 256 * k;            // oWTg[c][o] = oW[o][c]
            int c = idx >> 6, o = idx & 63;
            p.oWTg[idx] = p.oW[(size_t)o * 64 + c];
        }
    }
    gridbar(p.bar + 0);

    // ============ Phase B: conv3x3 (bx<256) || qkv (256<=bx<416) ============
    if (bx < 256) {
        int which = bx >> 7;
        int b     = (bx >> 6) & 1;
        int row   = bx & 63;
        const float* xb = p.x + (size_t)(b * 64) * HW;
#pragma unroll
        for (int it = 0; it < 24; it++) {
            int idx = t + 256 * it;
            int lr  = idx >> 11;
            int rem = idx & 2047;
            int icp = rem >> 6;
            int col = rem & 63;
            int ir  = row - 1 + lr;
            unsigned pack = 0;
            if (ir >= 0 && ir < 64) {
                float v0 = xb[(size_t)(icp * 2)     * HW + ir * 64 + col];
                float v1 = xb[(size_t)(icp * 2 + 1) * HW + ir * 64 + col];
                pack = (unsigned)f2bf(v0) | ((unsigned)f2bf(v1) << 16);
            }
            int icg = icp >> 2, io = icp & 3;
            *(unsigned*)&sm.xs[(((lr * 8 + icg) * 66 + col + 1) * 8) + io * 2] = pack;
        }
        if (t < 192) {
            int pair = t & 3;
            int colsel = (t >> 2) & 1;
            int rg = t >> 3;
            *(unsigned*)&sm.xs[((rg * 66 + colsel * 65) * 8) + pair * 2] = 0u;
        }
        __syncthreads();

        int lane = t & 63, w = t >> 6;
        int l31 = lane & 31, half = lane >> 5;
        int colh = w & 1;
        int m0   = (w >> 1) * 32;
        int c    = colh * 32 + l31;

        float16 acc;
#pragma unroll
        for (int i = 0; i < 16; i++) acc[i] = 0.f;

        const unsigned short* Wbase =
            p.Wa + ((size_t)which * 9) * 4096 + (size_t)(m0 + l31) * 64 + half * 8;

#pragma unroll
        for (int khw = 0; khw < 9; khw++) {
            const int kh = khw / 3, kw = khw % 3;
#pragma unroll
            for (int icq = 0; icq < 4; icq++) {
                short8 af = *(const short8*)(Wbase + (size_t)khw * 4096 + icq * 16);
                const unsigned short* bp =
                    &sm.xs[((kh * 8 + icq * 2 + half) * 66 + kw) * 8];
                short8 bf = *(const short8*)(bp + (size_t)c * 8);
                acc = __builtin_amdgcn_mfma_f32_32x32x16_bf16(af, bf, acc, 0, 0, 0);
            }
        }

        float* out = (which ? p.cx : p.sx) + (size_t)(b * 64) * HW;
        const float* sc = p.scsh + which * 128;
        int hwbase = row * 64 + c;
#pragma unroll
        for (int r = 0; r < 16; r++) {
            int oc = m0 + (r & 3) + 8 * (r >> 2) + 4 * half;
            float s  = sc[oc];
            float sh = sc[64 + oc];
            out[(size_t)oc * HW + hwbase] = fmaxf(acc[r] * s + sh, 0.f);
        }
    } else if (bx < 416) {
        int ubx = bx - 256;
        int b = ubx / 80, rem = ubx % 80;
        int chunk = rem / 5, g = rem % 5;
        int hw = chunk * 256 + t;
        const float* xb = p.x + (size_t)(b * 64) * HW + hw;

        float acc[16];
#pragma unroll
        for (int u = 0; u < 16; u++) acc[u] = 0.f;

        if (g == 0) {
            for (int ic = 0; ic < 64; ic++) {
                float xv = xb[ic * HW];
#pragma unroll
                for (int u = 0; u < 8; u++) acc[u]     += p.qW[u * 64 + ic] * xv;
#pragma unroll
                for (int u = 0; u < 8; u++) acc[8 + u] += p.kW[u * 64 + ic] * xv;
            }
            short8 qv, kv;
#pragma unroll
            for (int u = 0; u < 8; u++) qv[u] = (short)f2bf(acc[u] + p.qb[u]);
#pragma unroll
            for (int u = 0; u < 8; u++) kv[u] = (short)f2bf(acc[8 + u] + p.kb[u]);
            *(short8*)(p.qT + ((size_t)(b * HW) + hw) * 8) = qv;
            *(short8*)(p.kT + ((size_t)(b * HW) + hw) * 8) = kv;
        } else {
            int c0 = (g - 1) * 16;
            for (int ic = 0; ic < 64; ic++) {
                float xv = xb[ic * HW];
#pragma unroll
                for (int u = 0; u < 16; u++) acc[u] += p.vW[(c0 + u) * 64 + ic] * xv;
            }
            int m  = hw & 15;
            int sg = (m & 3) | ((m & 4) << 1) | ((m & 8) >> 1);   // sigma(m)
            size_t base = ((size_t)(b * 256) + (hw >> 4)) * 1024 + sg;
#pragma unroll
            for (int u = 0; u < 16; u++)
                p.vB[base + (size_t)(c0 + u) * 16] = f2bf(acc[u] + p.vb[c0 + u]);
        }
    }
    gridbar(p.bar + 1);

    // ============ Phase C: attn (all 512) + gram partials (bx>=448) ============
    {
        int lane = t & 63, w = t >> 6;
        int half = lane >> 5, l31 = lane & 31;
        int b  = bx >> 8;
        int itile = (bx >> 1) & 127;
        int jh = bx & 1;
        int i0 = itile * 32;

        short8 qf;
        if (half == 0) {
            qf = *(const short8*)(p.qT + ((size_t)(b * HW) + i0 + l31) * 8);
        } else {
#pragma unroll
            for (int i = 0; i < 8; i++) qf[i] = 0;
        }

        float16 o0, o1;
#pragma unroll
        for (int i = 0; i < 16; i++) { o0[i] = 0.f; o1[i] = 0.f; }
        float denr = 0.f;

        const unsigned short* kTb = p.kT + (size_t)(b * HW) * 8;
        const unsigned short* vBb = p.vB + (size_t)b * (256 * 1024);

        for (int tile = 0; tile < 16; tile++) {
            int j0 = jh * 2048 + w * 512 + tile * 32;
            int g0 = j0 >> 4;

            short8 kf;
            if (half == 0) {
                kf = *(const short8*)(kTb + (size_t)(j0 + l31) * 8);
            } else {
#pragma unroll
                for (int i = 0; i < 8; i++) kf[i] = 0;
            }

            float16 z;
#pragma unroll
            for (int i = 0; i < 16; i++) z[i] = 0.f;
            float16 s = __builtin_amdgcn_mfma_f32_32x32x16_bf16(kf, qf, z, 0, 0, 0);

            float pr[16];
#pragma unroll
            for (int r = 0; r < 16; r++) {
                pr[r] = __expf(s[r]);
                denr += pr[r];
            }
            short8 pa0, pa1;
#pragma unroll
            for (int r = 0; r < 8; r++) {
                pa0[r] = (short)f2bf(pr[r]);
                pa1[r] = (short)f2bf(pr[8 + r]);
            }

            const unsigned short* vg0 = vBb + (size_t)g0 * 1024 + half * 8;
            short8 v00 = *(const short8*)(vg0 + (size_t)l31 * 16);
            short8 v01 = *(const short8*)(vg0 + (size_t)(32 + l31) * 16);
            short8 v10 = *(const short8*)(vg0 + 1024 + (size_t)l31 * 16);
            short8 v11 = *(const short8*)(vg0 + 1024 + (size_t)(32 + l31) * 16);

            o0 = __builtin_amdgcn_mfma_f32_32x32x16_bf16(pa0, v00, o0, 0, 0, 0);
            o1 = __builtin_amdgcn_mfma_f32_32x32x16_bf16(pa0, v01, o1, 0, 0, 0);
            o0 = __builtin_amdgcn_mfma_f32_32x32x16_bf16(pa1, v10, o0, 0, 0, 0);
            o1 = __builtin_amdgcn_mfma_f32_32x32x16_bf16(pa1, v11, o1, 0, 0, 0);
        }

        float dfull = denr + __shfl_xor(denr, 32);
        if (half == 0) sm.at.den_sh[w][l31] = dfull;
#pragma unroll
        for (int r = 0; r < 16; r++) {
            int il = (r & 3) + 8 * (r >> 2) + 4 * half;
            sm.at.o_sh[w][l31][il]      = o0[r];
            sm.at.o_sh[w][32 + l31][il] = o1[r];
        }
        __syncthreads();

        int i  = t & 31;
        int cg = t >> 5;
        if (cg == 0)
            p.denp[jh * 8192 + b * 4096 + i0 + i] =
                sm.at.den_sh[0][i] + sm.at.den_sh[1][i] +
                sm.at.den_sh[2][i] + sm.at.den_sh[3][i];
#pragma unroll
        for (int u = 0; u < 8; u++) {
            int c = cg * 8 + u;
            float sv = sm.at.o_sh[0][c][i] + sm.at.o_sh[1][c][i]
                     + sm.at.o_sh[2][c][i] + sm.at.o_sh[3][c][i];
            p.Opart[((size_t)(jh * 2 + b) * 64 + c) * HW + i0 + i] = sv;
        }
    }
    if (bx >= 448) {
        // gram role: 64 units of 128 hw, 2 chunks of 64, acc in regs
        int gbx = bx - 448;
        int b = gbx >> 5, slice = gbx & 31;
        int i0 = (t & 15) * 4, j0c = (t >> 4) * 4;
        float acc[4][4] = {};
#pragma unroll
        for (int ch = 0; ch < 2; ch++) {
            int hwb = slice * 128 + ch * 64;
            __syncthreads();
#pragma unroll
            for (int it = 0; it < 16; it++) {
                int idx = t + 256 * it;          // 4096 = c(64) x hw(64)
                int hw = idx & 63, c = idx >> 6;
                sm.slab[hw][c] = p.cx[(size_t)(b * 64 + c) * HW + hwb + hw];
            }
            __syncthreads();
#pragma unroll 8
            for (int hw = 0; hw < 64; hw++) {
                float4 ai = *(const float4*)&sm.slab[hw][i0];
                float4 aj = *(const float4*)&sm.slab[hw][j0c];
                acc[0][0] += ai.x * aj.x; acc[0][1] += ai.x * aj.y;
                acc[0][2] += ai.x * aj.z; acc[0][3] += ai.x * aj.w;
                acc[1][0] += ai.y * aj.x; acc[1][1] += ai.y * aj.y;
                acc[1][2] += ai.y * aj.z; acc[1][3] += ai.y * aj.w;
                acc[2][0] += ai.z * aj.x; acc[2][1] += ai.z * aj.y;
                acc[2][2] += ai.z * aj.z; acc[2][3] += ai.z * aj.w;
                acc[3][0] += ai.w * aj.x; acc[3][1] += ai.w * aj.y;
                acc[3][2] += ai.w * aj.z; acc[3][3] += ai.w * aj.w;
            }
        }
        float* Gb = p.Gpart + ((size_t)(b * 32 + slice)) * 4096;
#pragma unroll
        for (int ii = 0; ii < 4; ii++)
            *(float4*)&Gb[(size_t)(i0 + ii) * 64 + j0c] =
                make_float4(acc[ii][0], acc[ii][1], acc[ii][2], acc[ii][3]);
    }
    gridbar(p.bar + 2);

    // ============ Phase C2: gram reduce + softmax (bx<2) ============
    if (bx < 2) {
        int b = bx;
#pragma unroll
        for (int k = 0; k < 16; k++) {
            int idx = t + 256 * k;
            float a = 0.f;
#pragma unroll 8
            for (int sl = 0; sl < 32; sl++)
                a += p.Gpart[((size_t)(b * 32 + sl)) * 4096 + idx];
            sm.d.u.A_raw[idx >> 6][idx & 63] = a;
        }
        __syncthreads();
        if (t < 64) {
            int i = t;
            float mn = sm.d.u.A_raw[i][0];
#pragma unroll 8
            for (int j = 1; j < 64; j++) mn = fminf(mn, sm.d.u.A_raw[i][j]);
            float ssum = 0.f;
#pragma unroll 8
            for (int j = 0; j < 64; j++) ssum += __expf(mn - sm.d.u.A_raw[i][j]);
            float inv = 1.f / ssum;
#pragma unroll 8
            for (int j = 0; j < 64; j++)
                p.ATg[(size_t)b * 4096 + j * 64 + i] =
                    __expf(mn - sm.d.u.A_raw[i][j]) * inv;
        }
    }
    gridbar(p.bar + 3);

    // ============ Phase D: fuse + out conv (all 512, 16-px chunks) ============
    {
        int b = bx >> 8, chunk = bx & 255;
        int px0 = chunk * 16;
        float sgam = p.s_gamma[0], cgam = p.c_gamma[0];

#pragma unroll
        for (int k = 0; k < 16; k++) {
            int idx = t + 256 * k;           // 4096
            int j = idx >> 6, i = idx & 63;
            sm.d.AT[j][i]      = p.ATg[(size_t)b * 4096 + idx];
            sm.d.u.f.oWT[j][i] = p.oWTg[idx];
        }
#pragma unroll
        for (int k = 0; k < 4; k++) {
            int idx = t + 256 * k;           // 1024 = c(64) x px(16)
            int c = idx >> 4, px = idx & 15;
            size_t o = (size_t)(b * 64 + c) * HW + px0 + px;
            float cv = p.cx[o];
            sm.d.u.f.cxs[c][px] = cv;
            float dd = p.denp[b * 4096 + px0 + px]
                     + p.denp[8192 + b * 4096 + px0 + px];
            float O = p.Opart[((size_t)(b) * 64 + c) * HW + px0 + px]
                    + p.Opart[((size_t)(2 + b) * 64 + c) * HW + px0 + px];
            sm.d.u.f.f_sh[c][px] = sgam * (O / dd) + p.sx[o] + cv;
        }
        __syncthreads();

        {
            int px = t & 15, cg = t >> 4;
            int c0 = cg * 4;
            float ca[4] = {};
            for (int j = 0; j < 64; j++) {
                float xv = sm.d.u.f.cxs[j][px];
                float4 a = *(const float4*)&sm.d.AT[j][c0];
                ca[0] += a.x * xv; ca[1] += a.y * xv;
                ca[2] += a.z * xv; ca[3] += a.w * xv;
            }
#pragma unroll
            for (int u = 0; u < 4; u++)
                sm.d.u.f.f_sh[c0 + u][px] += cgam * ca[u];
        }
        __syncthreads();

        {
            int px = t & 15, og = t >> 4;
            int o0 = og * 4;
            float acc[4] = {};
            for (int c = 0; c < 64; c++) {
                float fv = sm.d.u.f.f_sh[c][px];
                float4 wv = *(const float4*)&sm.d.u.f.oWT[c][o0];
                acc[0] += wv.x * fv; acc[1] += wv.y * fv;
                acc[2] += wv.z * fv; acc[3] += wv.w * fv;
            }
#pragma unroll
            for (int u = 0; u < 4; u++) {
                int o = o0 + u;
                p.out[(size_t)(b * 64 + o) * HW + px0 + px] = acc[u] + p.ob[o];
            }
        }
    }
}

// ---------------------------------------------------------------------------
extern "C" void kernel_launch(void* const* d_in, const int* in_sizes, int n_in,
                              void* d_out, int out_size, void* d_ws, size_t ws_size,
                              hipStream_t stream)
{
    float* ws = (float*)d_ws;

    Params P;
    P.x  = (const float*)d_in[0];
    P.sW = (const float*)d_in[1];  P.sb = (const float*)d_in[2];
    P.s_g = (const float*)d_in[3]; P.s_b = (const float*)d_in[4];
    P.s_m = (const float*)d_in[5]; P.s_v = (const float*)d_in[6];
    P.cW = (const float*)d_in[7];  P.cb = (const float*)d_in[8];
    P.c_g = (const float*)d_in[9]; P.c_b = (const float*)d_in[10];
    P.c_m = (const float*)d_in[11]; P.c_v = (const float*)d_in[12];
    P.qW = (const float*)d_in[13]; P.qb = (const float*)d_in[14];
    P.kW = (const float*)d_in[15]; P.kb = (const float*)d_in[16];
    P.vW = (const float*)d_in[17]; P.vb = (const float*)d_in[18];
    P.oW = (const float*)d_in[19]; P.ob = (const float*)d_in[20];
    P.s_gamma = (const float*)d_in[21];
    P.c_gamma = (const float*)d_in[22];
    P.out = (float*)d_out;

    P.sx    = ws;                  // 524288
    P.cx    = ws + 524288;         // 524288
    P.Opart = ws + 1048576;        // 1048576  [jh2][b2][64][HW]
    P.denp  = ws + 2097152;        // 16384    [jh2][b2][HW]
    P.ATg   = ws + 2113536;        // 8192     [b][j][i]
    P.Gpart = ws + 2121728;        // 262144   [b][32][64][64]
    P.oWTg  = ws + 2383872;        // 4096     [c][o]
    P.scsh  = ws + 2387968;        // 256
    P.bar   = (unsigned*)(ws + 2388224);   // 4 barrier cells (poison-healed)
    unsigned short* us = (unsigned short*)(ws + 2388240);
    P.qT = us;                     // 65536  [B][HW][8]
    P.kT = us + 65536;             // 65536  [B][HW][8]
    P.vB = us + 131072;            // 524288 [B][256][64][16] (j-blocked)
    P.Wa = us + 655360;            // 73728  [2][9][64oc][64ic]

    k_mega<<<NBLK, 256, 0, stream>>>(P);
}

// Round 8
// 159.191 us; speedup vs baseline: 2.3555x; 2.3555x over previous
//
#include <hip/hip_runtime.h>

#define HW 4096

typedef __attribute__((ext_vector_type(8)))  short short8;
typedef __attribute__((ext_vector_type(16))) float float16;

__device__ __forceinline__ unsigned short f2bf(float f) {
    unsigned u = __float_as_uint(f);
    u += 0x7fffu + ((u >> 16) & 1u);   // RNE
    return (unsigned short)(u >> 16);
}

// ---------------------------------------------------------------------------
// K0: weight prep. Wa[which][tap][oc][ic] bf16 + BN scale/shift + oW^T.
// grid 19.
// ---------------------------------------------------------------------------
__global__ __launch_bounds__(256) void k_wprep(
    const float* __restrict__ sW, const float* __restrict__ cW,
    const float* __restrict__ sb, const float* __restrict__ cb,
    const float* __restrict__ s_g, const float* __restrict__ s_b,
    const float* __restrict__ s_m, const float* __restrict__ s_v,
    const float* __restrict__ c_g, const float* __restrict__ c_b,
    const float* __restrict__ c_m, const float* __restrict__ c_v,
    const float* __restrict__ oW,
    unsigned short* __restrict__ Wa, float* __restrict__ scsh,
    float* __restrict__ oWTg)
{
    int bx = blockIdx.x;
    int t = threadIdx.x;
    if (bx < 18) {
        int which = bx / 9, khw = bx % 9;
        const float* W = which ? cW : sW;
#pragma unroll
        for (int i = 0; i < 16; i++) {
            int idx = t + 256 * i;            // 4096 = 64oc x 64ic
            int oc = idx >> 6, ic = idx & 63;
            float v = W[(size_t)(oc * 64 + ic) * 9 + khw];
            Wa[((size_t)(which * 9 + khw) * 64 + oc) * 64 + ic] = f2bf(v);
        }
        if (bx == 0 && t < 128) {
            int wh = t >> 6, oc = t & 63;
            const float* g  = wh ? c_g : s_g;
            const float* bb = wh ? c_b : s_b;
            const float* m  = wh ? c_m : s_m;
            const float* vv = wh ? c_v : s_v;
            const float* cbias = wh ? cb : sb;
            float scale = g[oc] * rsqrtf(vv[oc] + 1e-5f);
            scsh[wh * 128 + oc]      = scale;
            scsh[wh * 128 + 64 + oc] = (cbias[oc] - m[oc]) * scale + bb[oc];
        }
    } else {
#pragma unroll
        for (int k = 0; k < 16; k++) {
            int idx = t + 256 * k;            // oWTg[c][o] = oW[o][c]
            int c = idx >> 6, o = idx & 63;
            oWTg[idx] = oW[(size_t)o * 64 + c];
        }
    }
}

// ---------------------------------------------------------------------------
// KA: fused conv3x3(+BN+ReLU, MFMA) and 1x1 qkv projections.
// grid 416 = conv(256) + qkv(160). Conv staging uses float4 global loads.
// ---------------------------------------------------------------------------
__global__ __launch_bounds__(256, 3) void k_conv_qkv(
    const float* __restrict__ x, const unsigned short* __restrict__ Wa,
    const float* __restrict__ scsh,
    const float* __restrict__ qW, const float* __restrict__ qb,
    const float* __restrict__ kW, const float* __restrict__ kb,
    const float* __restrict__ vW, const float* __restrict__ vb,
    float* __restrict__ sx, float* __restrict__ cx,
    unsigned short* __restrict__ qT, unsigned short* __restrict__ kT,
    unsigned short* __restrict__ vB)
{
    __shared__ unsigned short xs[3 * 8 * 66 * 8];
    int bx = blockIdx.x;
    int t = threadIdx.x;

    if (bx < 256) {
        // ---------------- conv role ----------------
        int which = bx >> 7;
        int b     = (bx >> 6) & 1;
        int row   = bx & 63;
        const float* xb = x + (size_t)(b * 64) * HW;

#pragma unroll
        for (int it = 0; it < 6; it++) {
            int idx  = t + 256 * it;           // 1536 = lr(3) x icp(32) x col4(16)
            int col4 = idx & 15;
            int icp  = (idx >> 4) & 31;
            int lr   = idx >> 9;
            int ir   = row - 1 + lr;
            float fa[4] = {0.f, 0.f, 0.f, 0.f};
            float fb[4] = {0.f, 0.f, 0.f, 0.f};
            if (ir >= 0 && ir < 64) {
                const float* p0 = xb + (size_t)(icp * 2) * HW + ir * 64 + col4 * 4;
                float4 v0 = *(const float4*)p0;
                float4 v1 = *(const float4*)(p0 + HW);
                fa[0] = v0.x; fa[1] = v0.y; fa[2] = v0.z; fa[3] = v0.w;
                fb[0] = v1.x; fb[1] = v1.y; fb[2] = v1.z; fb[3] = v1.w;
            }
            int icg = icp >> 2, io = icp & 3;
#pragma unroll
            for (int j = 0; j < 4; j++) {
                unsigned pack = (unsigned)f2bf(fa[j]) | ((unsigned)f2bf(fb[j]) << 16);
                *(unsigned*)&xs[(((lr * 8 + icg) * 66 + col4 * 4 + j + 1) * 8) + io * 2] = pack;
            }
        }
        if (t < 192) {                          // zero cols 0 and 65
            int pair = t & 3;
            int colsel = (t >> 2) & 1;
            int rg = t >> 3;
            *(unsigned*)&xs[((rg * 66 + colsel * 65) * 8) + pair * 2] = 0u;
        }
        __syncthreads();

        int lane = t & 63, w = t >> 6;
        int l31 = lane & 31, half = lane >> 5;
        int colh = w & 1;
        int m0   = (w >> 1) * 32;
        int c    = colh * 32 + l31;

        float16 acc;
#pragma unroll
        for (int i = 0; i < 16; i++) acc[i] = 0.f;

        const unsigned short* Wbase =
            Wa + ((size_t)which * 9) * 4096 + (size_t)(m0 + l31) * 64 + half * 8;

#pragma unroll
        for (int khw = 0; khw < 9; khw++) {
            const int kh = khw / 3, kw = khw % 3;
#pragma unroll
            for (int icq = 0; icq < 4; icq++) {
                short8 af = *(const short8*)(Wbase + (size_t)khw * 4096 + icq * 16);
                const unsigned short* bp =
                    &xs[((kh * 8 + icq * 2 + half) * 66 + kw) * 8];
                short8 bf = *(const short8*)(bp + (size_t)c * 8);
                acc = __builtin_amdgcn_mfma_f32_32x32x16_bf16(af, bf, acc, 0, 0, 0);
            }
        }

        float* out = (which ? cx : sx) + (size_t)(b * 64) * HW;
        const float* sc = scsh + which * 128;
        int hwbase = row * 64 + c;
#pragma unroll
        for (int r = 0; r < 16; r++) {
            int oc = m0 + (r & 3) + 8 * (r >> 2) + 4 * half;
            float s  = sc[oc];
            float sh = sc[64 + oc];
            out[(size_t)oc * HW + hwbase] = fmaxf(acc[r] * s + sh, 0.f);
        }
    } else {
        // ---------------- qkv role ----------------
        int ubx = bx - 256;
        int b = ubx / 80, rem = ubx % 80;
        int chunk = rem / 5, g = rem % 5;
        int hw = chunk * 256 + t;
        const float* xb = x + (size_t)(b * 64) * HW + hw;

        float acc[16];
#pragma unroll
        for (int u = 0; u < 16; u++) acc[u] = 0.f;

        if (g == 0) {
            for (int ic = 0; ic < 64; ic++) {
                float xv = xb[ic * HW];
#pragma unroll
                for (int u = 0; u < 8; u++) acc[u]     += qW[u * 64 + ic] * xv;
#pragma unroll
                for (int u = 0; u < 8; u++) acc[8 + u] += kW[u * 64 + ic] * xv;
            }
            short8 qv, kv;
#pragma unroll
            for (int u = 0; u < 8; u++) qv[u] = (short)f2bf(acc[u] + qb[u]);
#pragma unroll
            for (int u = 0; u < 8; u++) kv[u] = (short)f2bf(acc[8 + u] + kb[u]);
            *(short8*)(qT + ((size_t)(b * HW) + hw) * 8) = qv;
            *(short8*)(kT + ((size_t)(b * HW) + hw) * 8) = kv;
        } else {
            int c0 = (g - 1) * 16;
            for (int ic = 0; ic < 64; ic++) {
                float xv = xb[ic * HW];
#pragma unroll
                for (int u = 0; u < 16; u++) acc[u] += vW[(c0 + u) * 64 + ic] * xv;
            }
            int m  = hw & 15;
            int sg = (m & 3) | ((m & 4) << 1) | ((m & 8) >> 1);   // sigma(m)
            size_t base = ((size_t)(b * 256) + (hw >> 4)) * 1024 + sg;
#pragma unroll
            for (int u = 0; u < 16; u++)
                vB[base + (size_t)(c0 + u) * 16] = f2bf(acc[u] + vb[c0 + u]);
        }
    }
}

// ---------------------------------------------------------------------------
// KB: fused spatial flash attention (j-split x4, unnormalized partials) and
// channel-gram partials. grid 1088 = attn(1024: b x itile x jh) + gram(64).
// launch_bounds(256,4) -> 4 blocks/CU for latency hiding.
// ---------------------------------------------------------------------------
union SmemKB {
    struct { float o_sh[4][64][33]; float den_sh[4][32]; } a;
    float slab[64][68];
};

__global__ __launch_bounds__(256, 4) void k_attn_gram(
    const unsigned short* __restrict__ qT, const unsigned short* __restrict__ kT,
    const unsigned short* __restrict__ vB, const float* __restrict__ cx,
    float* __restrict__ Opart, float* __restrict__ denp,
    float* __restrict__ Gpart)
{
    __shared__ SmemKB sm;
    int bx = blockIdx.x;
    int t = threadIdx.x;

    if (bx < 1024) {
        // ---------------- attention role ----------------
        int lane = t & 63, w = t >> 6;
        int half = lane >> 5, l31 = lane & 31;
        int b  = bx >> 9;
        int itile = (bx >> 2) & 127;
        int jh = bx & 3;
        int i0 = itile * 32;

        short8 qf;
        if (half == 0) {
            qf = *(const short8*)(qT + ((size_t)(b * HW) + i0 + l31) * 8);
        } else {
#pragma unroll
            for (int i = 0; i < 8; i++) qf[i] = 0;
        }

        float16 o0, o1;
#pragma unroll
        for (int i = 0; i < 16; i++) { o0[i] = 0.f; o1[i] = 0.f; }
        float denr = 0.f;

        const unsigned short* kTb = kT + (size_t)(b * HW) * 8;
        const unsigned short* vBb = vB + (size_t)b * (256 * 1024);

        for (int tile = 0; tile < 8; tile++) {
            int j0 = jh * 1024 + w * 256 + tile * 32;
            int g0 = j0 >> 4;

            short8 kf;
            if (half == 0) {
                kf = *(const short8*)(kTb + (size_t)(j0 + l31) * 8);
            } else {
#pragma unroll
                for (int i = 0; i < 8; i++) kf[i] = 0;
            }

            float16 z;
#pragma unroll
            for (int i = 0; i < 16; i++) z[i] = 0.f;
            float16 s = __builtin_amdgcn_mfma_f32_32x32x16_bf16(kf, qf, z, 0, 0, 0);

            float pr[16];
#pragma unroll
            for (int r = 0; r < 16; r++) {
                pr[r] = __expf(s[r]);
                denr += pr[r];
            }
            short8 pa0, pa1;
#pragma unroll
            for (int r = 0; r < 8; r++) {
                pa0[r] = (short)f2bf(pr[r]);
                pa1[r] = (short)f2bf(pr[8 + r]);
            }

            const unsigned short* vg0 = vBb + (size_t)g0 * 1024 + half * 8;
            short8 v00 = *(const short8*)(vg0 + (size_t)l31 * 16);
            short8 v01 = *(const short8*)(vg0 + (size_t)(32 + l31) * 16);
            short8 v10 = *(const short8*)(vg0 + 1024 + (size_t)l31 * 16);
            short8 v11 = *(const short8*)(vg0 + 1024 + (size_t)(32 + l31) * 16);

            o0 = __builtin_amdgcn_mfma_f32_32x32x16_bf16(pa0, v00, o0, 0, 0, 0);
            o1 = __builtin_amdgcn_mfma_f32_32x32x16_bf16(pa0, v01, o1, 0, 0, 0);
            o0 = __builtin_amdgcn_mfma_f32_32x32x16_bf16(pa1, v10, o0, 0, 0, 0);
            o1 = __builtin_amdgcn_mfma_f32_32x32x16_bf16(pa1, v11, o1, 0, 0, 0);
        }

        float dfull = denr + __shfl_xor(denr, 32);
        if (half == 0) sm.a.den_sh[w][l31] = dfull;
#pragma unroll
        for (int r = 0; r < 16; r++) {
            int il = (r & 3) + 8 * (r >> 2) + 4 * half;
            sm.a.o_sh[w][l31][il]      = o0[r];
            sm.a.o_sh[w][32 + l31][il] = o1[r];
        }
        __syncthreads();

        int i  = t & 31;
        int cg = t >> 5;
        if (cg == 0)
            denp[jh * 8192 + b * 4096 + i0 + i] =
                sm.a.den_sh[0][i] + sm.a.den_sh[1][i] +
                sm.a.den_sh[2][i] + sm.a.den_sh[3][i];
#pragma unroll
        for (int u = 0; u < 8; u++) {
            int c = cg * 8 + u;
            float sv = sm.a.o_sh[0][c][i] + sm.a.o_sh[1][c][i]
                     + sm.a.o_sh[2][c][i] + sm.a.o_sh[3][c][i];
            Opart[((size_t)(jh * 2 + b) * 64 + c) * HW + i0 + i] = sv;
        }
    } else {
        // ---------------- gram role: 64 blocks x 128 hw ----------------
        int gbx = bx - 1024;
        int b = gbx >> 5, slice = gbx & 31;
        int i0 = (t & 15) * 4, j0c = (t >> 4) * 4;
        float acc[4][4] = {};
#pragma unroll
        for (int ch = 0; ch < 2; ch++) {
            int hwb = slice * 128 + ch * 64;
            __syncthreads();
#pragma unroll
            for (int it = 0; it < 16; it++) {
                int idx = t + 256 * it;          // 4096 = c(64) x hw(64)
                int hw = idx & 63, c = idx >> 6;
                sm.slab[hw][c] = cx[(size_t)(b * 64 + c) * HW + hwb + hw];
            }
            __syncthreads();
#pragma unroll 8
            for (int hw = 0; hw < 64; hw++) {
                float4 ai = *(const float4*)&sm.slab[hw][i0];
                float4 aj = *(const float4*)&sm.slab[hw][j0c];
                acc[0][0] += ai.x * aj.x; acc[0][1] += ai.x * aj.y;
                acc[0][2] += ai.x * aj.z; acc[0][3] += ai.x * aj.w;
                acc[1][0] += ai.y * aj.x; acc[1][1] += ai.y * aj.y;
                acc[1][2] += ai.y * aj.z; acc[1][3] += ai.y * aj.w;
                acc[2][0] += ai.z * aj.x; acc[2][1] += ai.z * aj.y;
                acc[2][2] += ai.z * aj.z; acc[2][3] += ai.z * aj.w;
                acc[3][0] += ai.w * aj.x; acc[3][1] += ai.w * aj.y;
                acc[3][2] += ai.w * aj.z; acc[3][3] += ai.w * aj.w;
            }
        }
        float* Gb = Gpart + ((size_t)(b * 32 + slice)) * 4096;
#pragma unroll
        for (int ii = 0; ii < 4; ii++)
            *(float4*)&Gb[(size_t)(i0 + ii) * 64 + j0c] =
                make_float4(acc[ii][0], acc[ii][1], acc[ii][2], acc[ii][3]);
    }
}

// ---------------------------------------------------------------------------
// K4b: reduce 32 gram partials + row softmax(max-A) via min-trick.
// grid 32 x 256 (4 rows/block, one 64-lane wave per row). AcsT[b][j][i].
// ---------------------------------------------------------------------------
__global__ __launch_bounds__(256) void k_csoft(
    const float* __restrict__ Gpart, float* __restrict__ AcsT)
{
    int r = blockIdx.x * 4 + (threadIdx.x >> 6);
    int b = r >> 6, i = r & 63;
    int j = threadIdx.x & 63;

    const float* Gp = Gpart + (size_t)(b * 32) * 4096 + i * 64 + j;
    float a = 0.f;
#pragma unroll 8
    for (int sl = 0; sl < 32; sl++)
        a += Gp[(size_t)sl * 4096];

    float mn = a;
    mn = fminf(mn, __shfl_xor(mn, 1));
    mn = fminf(mn, __shfl_xor(mn, 2));
    mn = fminf(mn, __shfl_xor(mn, 4));
    mn = fminf(mn, __shfl_xor(mn, 8));
    mn = fminf(mn, __shfl_xor(mn, 16));
    mn = fminf(mn, __shfl_xor(mn, 32));
    float p = __expf(mn - a);
    float s = p;
    s += __shfl_xor(s, 1);
    s += __shfl_xor(s, 2);
    s += __shfl_xor(s, 4);
    s += __shfl_xor(s, 8);
    s += __shfl_xor(s, 16);
    s += __shfl_xor(s, 32);
    AcsT[(size_t)b * 4096 + j * 64 + i] = p / s;
}

// ---------------------------------------------------------------------------
// K5: fused epilogue: sa_map = sg*(SUM O)/(SUM d) + sx ; f = sa_map + cg*ca
// + cx ; out = oW @ f + ob. grid 256 = b(2) x chunk(128: 32 px).
// ---------------------------------------------------------------------------
__global__ __launch_bounds__(256) void k_fuse_out(
    const float* __restrict__ Opart, const float* __restrict__ denp,
    const float* __restrict__ sx,    const float* __restrict__ cx,
    const float* __restrict__ AcsT,
    const float* __restrict__ oWTg,  const float* __restrict__ ob,
    const float* __restrict__ s_gamma, const float* __restrict__ c_gamma,
    float* __restrict__ out)
{
    __shared__ float A_sh[64][68];    // A[j][i]
    __shared__ float cxs[64][33];     // cx[j][px]
    __shared__ float f_sh[64][33];    // fused[c][px]
    __shared__ float oWT[64][68];     // oW^T[c][o]

    int bx = blockIdx.x;
    int b = bx >> 7, chunk = bx & 127;
    int px0 = chunk * 32;
    int t = threadIdx.x;
    float sgam = s_gamma[0], cgam = c_gamma[0];

#pragma unroll
    for (int k = 0; k < 16; k++) {
        int idx = t + 256 * k;           // 4096
        int j = idx >> 6, i = idx & 63;
        A_sh[j][i] = AcsT[(size_t)b * 4096 + idx];
        oWT[j][i]  = oWTg[idx];
    }
#pragma unroll
    for (int k = 0; k < 8; k++) {
        int idx = t + 256 * k;           // 2048 = c(64) x px(32)
        int c = idx >> 5, px = idx & 31;
        size_t o = (size_t)(b * 64 + c) * HW + px0 + px;
        float cv = cx[o];
        cxs[c][px] = cv;
        float dd = denp[b * 4096 + px0 + px]
                 + denp[8192  + b * 4096 + px0 + px]
                 + denp[16384 + b * 4096 + px0 + px]
                 + denp[24576 + b * 4096 + px0 + px];
        float O = Opart[((size_t)(0 + b) * 64 + c) * HW + px0 + px]
                + Opart[((size_t)(2 + b) * 64 + c) * HW + px0 + px]
                + Opart[((size_t)(4 + b) * 64 + c) * HW + px0 + px]
                + Opart[((size_t)(6 + b) * 64 + c) * HW + px0 + px];
        f_sh[c][px] = sgam * (O / dd) + sx[o] + cv;
    }
    __syncthreads();

    {
        int px = t & 31, cg = t >> 5;
        int c0 = cg * 8;
        float ca[8] = {};
        for (int j = 0; j < 64; j++) {
            float xv = cxs[j][px];
            float4 a0 = *(const float4*)&A_sh[j][c0];
            float4 a1 = *(const float4*)&A_sh[j][c0 + 4];
            ca[0] += a0.x * xv; ca[1] += a0.y * xv;
            ca[2] += a0.z * xv; ca[3] += a0.w * xv;
            ca[4] += a1.x * xv; ca[5] += a1.y * xv;
            ca[6] += a1.z * xv; ca[7] += a1.w * xv;
        }
#pragma unroll
        for (int u = 0; u < 8; u++)
            f_sh[c0 + u][px] += cgam * ca[u];
    }
    __syncthreads();

    {
        int px = t & 31, og = t >> 5;
        int o0 = og * 8;
        float acc[8] = {};
        for (int c = 0; c < 64; c++) {
            float fv = f_sh[c][px];
            float4 a0 = *(const float4*)&oWT[c][o0];
            float4 a1 = *(const float4*)&oWT[c][o0 + 4];
            acc[0] += a0.x * fv; acc[1] += a0.y * fv;
            acc[2] += a0.z * fv; acc[3] += a0.w * fv;
            acc[4] += a1.x * fv; acc[5] += a1.y * fv;
            acc[6] += a1.z * fv; acc[7] += a1.w * fv;
        }
#pragma unroll
        for (int u = 0; u < 8; u++) {
            int o = o0 + u;
            out[(size_t)(b * 64 + o) * HW + px0 + px] = acc[u] + ob[o];
        }
    }
}

// ---------------------------------------------------------------------------
extern "C" void kernel_launch(void* const* d_in, const int* in_sizes, int n_in,
                              void* d_out, int out_size, void* d_ws, size_t ws_size,
                              hipStream_t stream)
{
    const float* x    = (const float*)d_in[0];
    const float* sW   = (const float*)d_in[1];
    const float* sb   = (const float*)d_in[2];
    const float* s_g  = (const float*)d_in[3];
    const float* s_b  = (const float*)d_in[4];
    const float* s_m  = (const float*)d_in[5];
    const float* s_v  = (const float*)d_in[6];
    const float* cW   = (const float*)d_in[7];
    const float* cb   = (const float*)d_in[8];
    const float* c_g  = (const float*)d_in[9];
    const float* c_b  = (const float*)d_in[10];
    const float* c_m  = (const float*)d_in[11];
    const float* c_v  = (const float*)d_in[12];
    const float* qW   = (const float*)d_in[13];
    const float* qb   = (const float*)d_in[14];
    const float* kW   = (const float*)d_in[15];
    const float* kb   = (const float*)d_in[16];
    const float* vW   = (const float*)d_in[17];
    const float* vb   = (const float*)d_in[18];
    const float* oW   = (const float*)d_in[19];
    const float* ob   = (const float*)d_in[20];
    const float* s_gamma = (const float*)d_in[21];
    const float* c_gamma = (const float*)d_in[22];

    float* ws    = (float*)d_ws;
    float* sx    = ws;                 // 524288
    float* cx    = ws + 524288;        // 524288
    float* Opart = ws + 1048576;       // 2097152  [jh4][b2][64][HW]
    float* denp  = ws + 3145728;       // 32768    [jh4][b2][HW]
    float* AcsT  = ws + 3178496;       // 8192     [b][j][i]
    float* Gpart = ws + 3186688;       // 262144   [b2][32][64][64]
    float* oWTg  = ws + 3448832;       // 4096     [c][o]
    float* scsh  = ws + 3452928;       // 256
    unsigned short* us = (unsigned short*)(ws + 3453184);
    unsigned short* qT = us;           // 65536  [B][HW][8]
    unsigned short* kT = us + 65536;   // 65536  [B][HW][8]
    unsigned short* vB = us + 131072;  // 524288 [B][256][64][16] (j-blocked)
    unsigned short* Wa = us + 655360;  // 73728  [2][9][64oc][64ic]

    k_wprep<<<19, 256, 0, stream>>>(sW, cW, sb, cb, s_g, s_b, s_m, s_v,
                                    c_g, c_b, c_m, c_v, oW, Wa, scsh, oWTg);
    k_conv_qkv<<<416, 256, 0, stream>>>(x, Wa, scsh, qW, qb, kW, kb, vW, vb,
                                        sx, cx, qT, kT, vB);
    k_attn_gram<<<1088, 256, 0, stream>>>(qT, kT, vB, cx, Opart, denp, Gpart);
    k_csoft<<<32, 256, 0, stream>>>(Gpart, AcsT);
    k_fuse_out<<<256, 256, 0, stream>>>(Opart, denp, sx, cx, AcsT,
                                        oWTg, ob, s_gamma, c_gamma, (float*)d_out);
}